// Round 1
// baseline (659.330 us; speedup 1.0000x reference)
//
#include <hip/hip_runtime.h>
#include <hip/hip_bf16.h>

// Problem constants (StyledConv): B=8, Cin=Cout=64, H=W=256, S=512, K=3
#define BB   8
#define CC   64
#define HH   256
#define WW   256
#define SS   512
#define HW   (HH*WW)

#define LIN_SCALE  0.044194173824159216f   // 1/sqrt(512)
#define CONV_SCALE 0.041666666666666664f   // 1/sqrt(64*9) = 1/24
#define LRELU      0.2f
#define GAIN       1.4142135623730951f

// ---------------- Kernel A: s[b][ci] = style[b,:] @ mod_w[:,ci] * lin_scale + mod_b[ci]
__global__ void mod_kernel(const float* __restrict__ style,
                           const float* __restrict__ mod_w,
                           const float* __restrict__ mod_b,
                           float* __restrict__ s_out) {
    int b = blockIdx.x;        // 0..7
    int ci = threadIdx.x;      // 0..63
    float acc = 0.f;
    const float* st = style + b * SS;
    for (int k = 0; k < SS; ++k)
        acc = fmaf(st[k], mod_w[k * CC + ci], acc);
    s_out[b * CC + ci] = acc * LIN_SCALE + mod_b[ci];
}

// ---------------- Kernel B: modulate + demod, store wmod[b][ci][co][12] (9 used, 3 pad)
__global__ void wmod_kernel(const float* __restrict__ weight,
                            const float* __restrict__ s_in,
                            float* __restrict__ wmod) {
    int bc = blockIdx.x;                // b*64 + co
    int b = bc >> 6, co = bc & 63;
    int ci = threadIdx.x;               // 0..63 (one wave)
    float w[9];
    float sv = s_in[b * CC + ci] * CONV_SCALE;
    float sum = 0.f;
    const float* wp = weight + (co * CC + ci) * 9;
#pragma unroll
    for (int k = 0; k < 9; ++k) {
        w[k] = wp[k] * sv;
        sum = fmaf(w[k], w[k], sum);
    }
    // reduce over all 64 lanes (sum over ci and k)
#pragma unroll
    for (int off = 32; off; off >>= 1)
        sum += __shfl_xor(sum, off);
    float demod = rsqrtf(sum + 1e-8f);
    float* dst = wmod + ((size_t)(b * CC + ci) * CC + co) * 12;
#pragma unroll
    for (int k = 0; k < 9; ++k) dst[k] = w[k] * demod;
    dst[9] = 0.f; dst[10] = 0.f; dst[11] = 0.f;
}

// ---------------- Kernel C: conv 3x3 + noise + bias + leaky_relu * gain
// Block: 256 threads; tile = 32x32 pixels, 16 output channels.
// Thread: 4 consecutive x-pixels x 16 co accumulators (64 f32 acc).
#define XS_STRIDE 37   // pad: max 2-way LDS bank aliasing (free)
__global__ __launch_bounds__(256) void conv_kernel(
        const float* __restrict__ x,
        const float* __restrict__ noise,
        const float* __restrict__ nwp,
        const float* __restrict__ bias,
        const float* __restrict__ wmod,
        float* __restrict__ out) {
    __shared__ float xs[34][XS_STRIDE];
    __shared__ float wsh[16][12];

    int bx = blockIdx.x;            // 0..7  (W/32)
    int by = blockIdx.y;            // 0..7  (H/32)
    int bz = blockIdx.z;            // b*4 + cog
    int b = bz >> 2;
    int co0 = (bz & 3) * 16;
    int x0 = bx * 32, y0 = by * 32;

    int t = threadIdx.x;
    int tx = (t & 7) * 4;           // 0..28
    int ty = t >> 3;                // 0..31

    float acc[16][4];
#pragma unroll
    for (int j = 0; j < 16; ++j)
#pragma unroll
        for (int p = 0; p < 4; ++p) acc[j][p] = 0.f;

    const float* xb = x + (size_t)b * CC * HW;

    for (int ci = 0; ci < CC; ++ci) {
        __syncthreads();
        // stage 34x34 x-tile (halo 1, zero-padded at image border)
        const float* xc = xb + (size_t)ci * HW;
        for (int i = t; i < 34 * 34; i += 256) {
            int r = i / 34, c = i % 34;
            int gy = y0 - 1 + r, gx = x0 - 1 + c;
            float v = 0.f;
            if ((unsigned)gy < (unsigned)HH && (unsigned)gx < (unsigned)WW)
                v = xc[gy * WW + gx];
            xs[r][c] = v;
        }
        // stage 16 co x 12 weights (contiguous in wmod layout)
        if (t < 192) {
            ((float*)wsh)[t] = wmod[((size_t)(b * CC + ci) * CC + co0) * 12 + t];
        }
        __syncthreads();

        // per-thread x neighborhood: 3 rows x 6 cols
        float xr[3][6];
#pragma unroll
        for (int r = 0; r < 3; ++r)
#pragma unroll
            for (int c = 0; c < 6; ++c)
                xr[r][c] = xs[ty + r][tx + c];

#pragma unroll
        for (int j = 0; j < 16; ++j) {
            float4 w0 = *(const float4*)&wsh[j][0];
            float4 w1 = *(const float4*)&wsh[j][4];
            float w8 = wsh[j][8];
            float w[9] = {w0.x, w0.y, w0.z, w0.w, w1.x, w1.y, w1.z, w1.w, w8};
#pragma unroll
            for (int p = 0; p < 4; ++p) {
                float sacc = acc[j][p];
#pragma unroll
                for (int kh = 0; kh < 3; ++kh)
#pragma unroll
                    for (int kw = 0; kw < 3; ++kw)
                        sacc = fmaf(xr[kh][p + kw], w[kh * 3 + kw], sacc);
                acc[j][p] = sacc;
            }
        }
    }

    // epilogue
    float nwv = nwp[0];
    int py = y0 + ty;
    float nz[4];
    const float* np_ = noise + (size_t)b * HW + py * WW + x0 + tx;
#pragma unroll
    for (int p = 0; p < 4; ++p) nz[p] = nwv * np_[p];

#pragma unroll
    for (int j = 0; j < 16; ++j) {
        int co = co0 + j;
        float bv = bias[co];
        float* op = out + ((size_t)b * CC + co) * HW + py * WW + x0 + tx;
        float tmp[4];
#pragma unroll
        for (int p = 0; p < 4; ++p) {
            float v = acc[j][p] + nz[p] + bv;
            v = (v > 0.f ? v : LRELU * v) * GAIN;
            tmp[p] = v;
        }
        *(float4*)op = make_float4(tmp[0], tmp[1], tmp[2], tmp[3]);
    }
}

extern "C" void kernel_launch(void* const* d_in, const int* in_sizes, int n_in,
                              void* d_out, int out_size, void* d_ws, size_t ws_size,
                              hipStream_t stream) {
    const float* x       = (const float*)d_in[0];
    const float* style   = (const float*)d_in[1];
    const float* noise   = (const float*)d_in[2];
    const float* weight  = (const float*)d_in[3];
    const float* mod_w   = (const float*)d_in[4];
    const float* mod_b   = (const float*)d_in[5];
    const float* nw      = (const float*)d_in[6];
    const float* bias    = (const float*)d_in[7];
    float* out = (float*)d_out;

    float* s_buf = (float*)d_ws;                       // 8*64 floats
    float* wmod  = (float*)((char*)d_ws + 4096);       // 8*64*64*12 floats = 1.5 MB

    mod_kernel<<<dim3(BB), dim3(CC), 0, stream>>>(style, mod_w, mod_b, s_buf);
    wmod_kernel<<<dim3(BB * CC), dim3(CC), 0, stream>>>(weight, s_buf, wmod);
    conv_kernel<<<dim3(WW / 32, HH / 32, BB * 4), dim3(256), 0, stream>>>(
        x, noise, nw, bias, wmod, out);
}

// Round 2
// 193.356 us; speedup vs baseline: 3.4099x; 3.4099x over previous
//
#include <hip/hip_runtime.h>
#include <hip/hip_bf16.h>

// StyledConv: B=8, Cin=Cout=64, H=W=256, S=512, K=3
#define BB   8
#define CC   64
#define HH   256
#define WW   256
#define SS   512
#define HW   (HH*WW)

#define LIN_SCALE  0.044194173824159216f   // 1/sqrt(512)
#define CONV_SCALE 0.041666666666666664f   // 1/24
#define LRELU      0.2f
#define GAIN       1.4142135623730951f

typedef __attribute__((ext_vector_type(8))) short short8;     // 8 bf16 (A/B frag)
typedef __attribute__((ext_vector_type(4))) float floatx4;    // C/D frag
typedef __attribute__((ext_vector_type(8))) unsigned short ushort8;

static __device__ __forceinline__ unsigned short f2bf(float f) {
    unsigned u = __float_as_uint(f);
    u += 0x7FFF + ((u >> 16) & 1);          // RNE to bf16 (inputs are finite)
    return (unsigned short)(u >> 16);
}

// ---------------- Kernel A: s[b][ci] = style[b,:] @ mod_w[:,ci] * lin_scale + mod_b[ci]
__global__ void mod_kernel(const float* __restrict__ style,
                           const float* __restrict__ mod_w,
                           const float* __restrict__ mod_b,
                           float* __restrict__ s_out) {
    int b = blockIdx.x;        // 0..7
    int ci = threadIdx.x;      // 0..63
    float acc = 0.f;
    const float* st = style + b * SS;
    for (int k = 0; k < SS; ++k)
        acc = fmaf(st[k], mod_w[k * CC + ci], acc);
    s_out[b * CC + ci] = acc * LIN_SCALE + mod_b[ci];
}

// ---------------- Kernel B: modulate + demod (f32), emit bf16 weights in
// A-fragment layout: wbf[b][ko 9][cic 2][cig 4][co 64][j 8]  (ci = cic*32+cig*8+j)
__global__ void wmod_kernel(const float* __restrict__ weight,
                            const float* __restrict__ s_in,
                            unsigned short* __restrict__ wbf) {
    int bc = blockIdx.x;                // b*64 + co
    int b = bc >> 6, co = bc & 63;
    int ci = threadIdx.x;               // 0..63 (one wave)
    float wv[9];
    float sv = s_in[b * CC + ci] * CONV_SCALE;
    float sum = 0.f;
    const float* wp = weight + (co * CC + ci) * 9;
#pragma unroll
    for (int k = 0; k < 9; ++k) {
        wv[k] = wp[k] * sv;
        sum = fmaf(wv[k], wv[k], sum);
    }
#pragma unroll
    for (int off = 32; off; off >>= 1)
        sum += __shfl_xor(sum, off);
    float demod = rsqrtf(sum + 1e-8f);
    int cic = ci >> 5, cg = (ci >> 3) & 3, j = ci & 7;
#pragma unroll
    for (int ko = 0; ko < 9; ++ko) {
        size_t idx = (((((size_t)b * 9 + ko) * 2 + cic) * 4 + cg) * 64 + co) * 8 + j;
        wbf[idx] = f2bf(wv[ko] * demod);
    }
}

// ---------------- Kernel C: implicit-GEMM conv via MFMA 16x16x32 bf16
// Block: 256 thr (4 waves). Pixel tile 16 rows x 32 cols; all 64 co.
// Wave w: rows w*4..w*4+3 (8 N-tiles of 16 px), 4 M-tiles of 16 co.
// LDS: x chunk [18 y][34 x][32 ci] bf16, XOR-swizzled (byte ^= (x&7)<<4).
__global__ __launch_bounds__(256, 2) void conv_kernel(
        const float* __restrict__ x,
        const float* __restrict__ noise,
        const float* __restrict__ nwp,
        const float* __restrict__ bias,
        const unsigned short* __restrict__ wbf,
        float* __restrict__ out) {
    __shared__ unsigned short xs[18 * 34 * 32];   // 39168 B

    const int t = threadIdx.x;
    const int lane = t & 63;
    const int wv = t >> 6;          // wave 0..3
    const int l15 = lane & 15;
    const int cg = lane >> 4;       // 0..3
    const int x0t = blockIdx.x * 32;
    const int y0t = blockIdx.y * 16;
    const int b   = blockIdx.z;
    const int wr  = wv * 4;         // wave's local row base

    floatx4 acc[4][8];
#pragma unroll
    for (int mt = 0; mt < 4; ++mt)
#pragma unroll
        for (int nt = 0; nt < 8; ++nt) acc[mt][nt] = (floatx4)0.f;

    float bv[4][4];
#pragma unroll
    for (int mt = 0; mt < 4; ++mt)
#pragma unroll
        for (int j = 0; j < 4; ++j) bv[mt][j] = bias[mt * 16 + cg * 4 + j];

    const int scig = t & 3;         // 8-ci subgroup (of 32-chunk) for staging
    const int sp0  = t >> 2;        // 0..63 position lane

    for (int cic = 0; cic < 2; ++cic) {
        __syncthreads();
        // ---- stage 18x34 x 32ci (f32 -> bf16, swizzled)
#pragma unroll
        for (int it = 0; it < 10; ++it) {
            int p = sp0 + it * 64;            // 0..639, valid < 612
            if (p < 612) {
                int y = p / 34, xc = p - y * 34;
                int gy = y0t + y - 1, gx = x0t + xc - 1;
                bool inb = ((unsigned)gy < HH) && ((unsigned)gx < WW);
                const float* xp = x + ((size_t)b * CC + cic * 32 + scig * 8) * HW
                                    + gy * WW + gx;
                ushort8 pk;
#pragma unroll
                for (int k = 0; k < 8; ++k) {
                    float v = inb ? xp[(size_t)k * HW] : 0.f;
                    pk[k] = f2bf(v);
                }
                unsigned off = ((unsigned)(p * 32 + scig * 8) * 2) ^ ((unsigned)(xc & 7) << 4);
                *(ushort8*)((char*)xs + off) = pk;
            }
        }
        __syncthreads();

        // ---- 9 offsets x K=32 MFMA
#pragma unroll
        for (int kh = 0; kh < 3; ++kh) {
#pragma unroll
            for (int kw = 0; kw < 3; ++kw) {
                const int ko = kh * 3 + kw;
                short8 a[4];
                const unsigned short* wp = wbf +
                    (((((size_t)b * 9 + ko) * 2 + cic) * 4 + cg) * 64) * 8;
#pragma unroll
                for (int mt = 0; mt < 4; ++mt)
                    a[mt] = *(const short8*)(wp + (mt * 16 + l15) * 8);
#pragma unroll
                for (int nt = 0; nt < 8; ++nt) {
                    int r = nt >> 1, h = nt & 1;
                    int ys = wr + r + kh;
                    int xc = h * 16 + l15 + kw;
                    unsigned off = ((unsigned)((ys * 34 + xc) * 32 + cg * 8) * 2)
                                   ^ ((unsigned)(xc & 7) << 4);
                    short8 bf = *(const short8*)((const char*)xs + off);
#pragma unroll
                    for (int mt = 0; mt < 4; ++mt)
                        acc[mt][nt] = __builtin_amdgcn_mfma_f32_16x16x32_bf16(
                            a[mt], bf, acc[mt][nt], 0, 0, 0);
                }
            }
        }
    }

    // ---- epilogue: noise + bias + leaky_relu * gain
    float nw = nwp[0];
#pragma unroll
    for (int nt = 0; nt < 8; ++nt) {
        int r = nt >> 1, h = nt & 1;
        int py = y0t + wr + r;
        int px = x0t + h * 16 + l15;
        float nz = nw * noise[(size_t)b * HW + py * WW + px];
#pragma unroll
        for (int mt = 0; mt < 4; ++mt) {
#pragma unroll
            for (int j = 0; j < 4; ++j) {
                int co = mt * 16 + cg * 4 + j;
                float v = acc[mt][nt][j] + nz + bv[mt][j];
                v = (v > 0.f ? v : LRELU * v) * GAIN;
                out[((size_t)b * CC + co) * HW + (size_t)py * WW + px] = v;
            }
        }
    }
}

extern "C" void kernel_launch(void* const* d_in, const int* in_sizes, int n_in,
                              void* d_out, int out_size, void* d_ws, size_t ws_size,
                              hipStream_t stream) {
    const float* x       = (const float*)d_in[0];
    const float* style   = (const float*)d_in[1];
    const float* noise   = (const float*)d_in[2];
    const float* weight  = (const float*)d_in[3];
    const float* mod_w   = (const float*)d_in[4];
    const float* mod_b   = (const float*)d_in[5];
    const float* nw      = (const float*)d_in[6];
    const float* bias    = (const float*)d_in[7];
    float* out = (float*)d_out;

    float* s_buf          = (float*)d_ws;                         // 2 KB
    unsigned short* wbf   = (unsigned short*)((char*)d_ws + 4096); // 8*9*2*4*64*8*2B = 576 KB

    mod_kernel<<<dim3(BB), dim3(CC), 0, stream>>>(style, mod_w, mod_b, s_buf);
    wmod_kernel<<<dim3(BB * CC), dim3(CC), 0, stream>>>(weight, s_buf, wbf);
    conv_kernel<<<dim3(WW / 32, HH / 16, BB), dim3(256), 0, stream>>>(
        x, noise, nw, bias, wbf, out);
}

// Round 4
// 107.113 us; speedup vs baseline: 6.1554x; 1.8052x over previous
//
#include <hip/hip_runtime.h>
#include <hip/hip_bf16.h>

// StyledConv: B=8, Cin=Cout=64, H=W=256, S=512, K=3
#define BB   8
#define CC   64
#define HH   256
#define WW   256
#define SS   512
#define HW   (HH*WW)

#define LIN_SCALE  0.044194173824159216f   // 1/sqrt(512)
#define CONV_SCALE 0.041666666666666664f   // 1/24
#define LRELU      0.2f
#define GAIN       1.4142135623730951f

// conv tile: 8 rows x 32 cols out, all 64 co, all 64 ci staged once
#define TY 8
#define TX 32
#define LY (TY + 2)   // 10
#define LX (TX + 2)   // 34

typedef __attribute__((ext_vector_type(8))) short short8;            // A/B frag (8 bf16)
typedef __attribute__((ext_vector_type(4))) float floatx4;           // C/D frag
typedef __attribute__((ext_vector_type(4))) unsigned short bfx4;     // 8B LDS write

static __device__ __forceinline__ unsigned short f2bf(float f) {
    unsigned u = __float_as_uint(f);
    u += 0x7FFF + ((u >> 16) & 1);          // RNE (inputs finite)
    return (unsigned short)(u >> 16);
}

// ---------------- Kernel A: s[b][ci] = style[b,:] @ mod_w[:,ci] * lin_scale + mod_b
__global__ void mod_kernel(const float* __restrict__ style,
                           const float* __restrict__ mod_w,
                           const float* __restrict__ mod_b,
                           float* __restrict__ s_out) {
    __shared__ float part[256];
    int b = blockIdx.x;
    int t = threadIdx.x;
    int ci = t & 63, kp = t >> 6;
    const float* st = style + b * SS + kp * 128;
    float acc = 0.f;
    for (int k = 0; k < 128; ++k)
        acc = fmaf(st[k], mod_w[(kp * 128 + k) * CC + ci], acc);
    part[t] = acc;
    __syncthreads();
    if (t < 64) {
        float v = part[t] + part[t + 64] + part[t + 128] + part[t + 192];
        s_out[b * CC + t] = v * LIN_SCALE + mod_b[t];
    }
}

// ---------------- Kernel B: modulate + demod (f32), bf16 weights in A-frag layout
// wbf[b][ko 9][cic 2][cg 4][co 64][j 8]   (ci = cic*32 + cg*8 + j)
__global__ void wmod_kernel(const float* __restrict__ weight,
                            const float* __restrict__ s_in,
                            unsigned short* __restrict__ wbf) {
    int bc = blockIdx.x;                // b*64 + co
    int b = bc >> 6, co = bc & 63;
    int ci = threadIdx.x;               // one wave
    float wv[9];
    float sv = s_in[b * CC + ci] * CONV_SCALE;
    float sum = 0.f;
    const float* wp = weight + (co * CC + ci) * 9;
#pragma unroll
    for (int k = 0; k < 9; ++k) {
        wv[k] = wp[k] * sv;
        sum = fmaf(wv[k], wv[k], sum);
    }
#pragma unroll
    for (int off = 32; off; off >>= 1)
        sum += __shfl_xor(sum, off);
    float demod = rsqrtf(sum + 1e-8f);
    int cic = ci >> 5, cg = (ci >> 3) & 3, j = ci & 7;
#pragma unroll
    for (int ko = 0; ko < 9; ++ko) {
        size_t idx = (((((size_t)b * 9 + ko) * 2 + cic) * 4 + cg) * 64 + co) * 8 + j;
        wbf[idx] = f2bf(wv[ko] * demod);
    }
}

// ---------------- Kernel C: implicit-GEMM conv, MFMA 16x16x32 bf16
// LDS x-tile [LY][LX][64ci] bf16, swizzle byte ^= (x&7)<<4. One stage, one barrier.
__global__ __launch_bounds__(256, 3) void conv_kernel(
        const float* __restrict__ x,
        const float* __restrict__ noise,
        const float* __restrict__ nwp,
        const float* __restrict__ bias,
        const unsigned short* __restrict__ wbf,
        float* __restrict__ out) {
    __shared__ unsigned short xs[LY * LX * 64];   // 43520 B

    // bijective XCD swizzle: XCD c processes batch image b=c, rows top->bottom
    const int lin  = blockIdx.x;                 // 0..2047
    const int lin2 = (lin & 7) * 256 + (lin >> 3);
    const int b   = lin2 >> 8;
    const int rem = lin2 & 255;
    const int by  = rem >> 3;
    const int bx  = rem & 7;
    const int x0t = bx * TX;
    const int y0t = by * TY;

    const int t = threadIdx.x;
    const int lane = t & 63;
    const int wv = t >> 6;
    const int l15 = lane & 15;
    const int cg = lane >> 4;      // 0..3
    const int wr = wv * 2;         // wave's out-row base

    // ---- stage: 10 rows x 40 px (aligned float4) x 64 ci, f32->bf16
    const int NTASK = LY * 16 * 10;   // (y, ciq, q) = 1600
    for (int task = t; task < NTASK; task += 256) {
        int q = task % 10;
        int rest = task / 10;
        int ciq = rest & 15;
        int yl = rest >> 4;             // 0..9
        int gy = y0t + yl - 1;
        int gx0 = x0t - 4 + q * 4;      // 16B aligned
        bool rowok = (unsigned)gy < (unsigned)HH;
        float va[4][4];
        if (rowok && (unsigned)gx0 <= (unsigned)(WW - 4)) {
            const float* xp = x + ((size_t)b * CC + ciq * 4) * HW + (size_t)gy * WW + gx0;
#pragma unroll
            for (int c = 0; c < 4; ++c) {
                float4 f = *(const float4*)(xp + (size_t)c * HW);
                va[c][0] = f.x; va[c][1] = f.y; va[c][2] = f.z; va[c][3] = f.w;
            }
        } else {
            const float* xp = x + ((size_t)b * CC + ciq * 4) * HW + (size_t)gy * WW;
#pragma unroll
            for (int c = 0; c < 4; ++c)
#pragma unroll
                for (int k = 0; k < 4; ++k) {
                    int gx = gx0 + k;
                    va[c][k] = (rowok && (unsigned)gx < (unsigned)WW)
                               ? xp[(size_t)c * HW + gx] : 0.f;
                }
        }
#pragma unroll
        for (int k = 0; k < 4; ++k) {
            int lx = 4 * q - 3 + k;
            if ((unsigned)lx < (unsigned)LX) {
                bfx4 pk;
                pk[0] = f2bf(va[0][k]); pk[1] = f2bf(va[1][k]);
                pk[2] = f2bf(va[2][k]); pk[3] = f2bf(va[3][k]);
                unsigned off = ((unsigned)((yl * LX + lx) * 64 + ciq * 4) * 2)
                               ^ ((unsigned)(lx & 7) << 4);
                *(bfx4*)((char*)xs + off) = pk;
            }
        }
    }
    __syncthreads();

    // ---- compute: 9 taps x 2 ci-chunks x MFMA
    floatx4 acc[4][4];
#pragma unroll
    for (int mt = 0; mt < 4; ++mt)
#pragma unroll
        for (int nt = 0; nt < 4; ++nt) acc[mt][nt] = (floatx4)0.f;

#pragma unroll
    for (int kh = 0; kh < 3; ++kh) {
#pragma unroll
        for (int kw = 0; kw < 3; ++kw) {
            const int ko = kh * 3 + kw;
#pragma unroll
            for (int cic = 0; cic < 2; ++cic) {
                short8 a[4];
                const unsigned short* wp = wbf +
                    (((((size_t)b * 9 + ko) * 2 + cic) * 4 + cg) * 64) * 8;
#pragma unroll
                for (int mt = 0; mt < 4; ++mt)
                    a[mt] = *(const short8*)(wp + (mt * 16 + l15) * 8);
#pragma unroll
                for (int nt = 0; nt < 4; ++nt) {
                    int r = nt >> 1, h = nt & 1;
                    int ys = wr + r + kh;
                    int xl = h * 16 + l15 + kw;
                    unsigned off = ((unsigned)((ys * LX + xl) * 64 + cic * 32 + cg * 8) * 2)
                                   ^ ((unsigned)(xl & 7) << 4);
                    short8 bf = *(const short8*)((const char*)xs + off);
#pragma unroll
                    for (int mt = 0; mt < 4; ++mt)
                        acc[mt][nt] = __builtin_amdgcn_mfma_f32_16x16x32_bf16(
                            a[mt], bf, acc[mt][nt], 0, 0, 0);
                }
            }
        }
    }

    // ---- epilogue: noise + bias + leaky_relu * gain
    float nw = nwp[0];
    float bv[4][4];
#pragma unroll
    for (int mt = 0; mt < 4; ++mt)
#pragma unroll
        for (int j = 0; j < 4; ++j) bv[mt][j] = bias[mt * 16 + cg * 4 + j];

#pragma unroll
    for (int nt = 0; nt < 4; ++nt) {
        int r = nt >> 1, h = nt & 1;
        int py = y0t + wr + r;
        int px = x0t + h * 16 + l15;
        float nz = nw * noise[(size_t)b * HW + (size_t)py * WW + px];
#pragma unroll
        for (int mt = 0; mt < 4; ++mt) {
#pragma unroll
            for (int j = 0; j < 4; ++j) {
                int co = mt * 16 + cg * 4 + j;
                float v = acc[mt][nt][j] + nz + bv[mt][j];
                v = (v > 0.f ? v : LRELU * v) * GAIN;
                out[((size_t)b * CC + co) * HW + (size_t)py * WW + px] = v;
            }
        }
    }
}

extern "C" void kernel_launch(void* const* d_in, const int* in_sizes, int n_in,
                              void* d_out, int out_size, void* d_ws, size_t ws_size,
                              hipStream_t stream) {
    const float* x       = (const float*)d_in[0];
    const float* style   = (const float*)d_in[1];
    const float* noise   = (const float*)d_in[2];
    const float* weight  = (const float*)d_in[3];
    const float* mod_w   = (const float*)d_in[4];
    const float* mod_b   = (const float*)d_in[5];
    const float* nw      = (const float*)d_in[6];
    const float* bias    = (const float*)d_in[7];
    float* out = (float*)d_out;

    float* s_buf          = (float*)d_ws;                          // 2 KB
    unsigned short* wbf   = (unsigned short*)((char*)d_ws + 4096); // 576 KB

    mod_kernel<<<dim3(BB), dim3(256), 0, stream>>>(style, mod_w, mod_b, s_buf);
    wmod_kernel<<<dim3(BB * CC), dim3(CC), 0, stream>>>(weight, s_buf, wbf);
    conv_kernel<<<dim3((WW / TX) * (HH / TY) * BB), dim3(256), 0, stream>>>(
        x, noise, nw, bias, wbf, out);
}